// Round 4
// baseline (546.439 us; speedup 1.0000x reference)
//
#include <hip/hip_runtime.h>

#define NNODE 10000
#define NEDGE 160000
#define DD 256

using f32x4  = __attribute__((ext_vector_type(4))) float;
using bf16x8 = __attribute__((ext_vector_type(8))) short;
using u32x4  = __attribute__((ext_vector_type(4))) unsigned;

__device__ inline short f2bf(float f) {
  unsigned u = __float_as_uint(f);
  unsigned r = (u + 0x7fffu + ((u >> 16) & 1u)) >> 16;
  return (short)(unsigned short)r;
}

__device__ inline unsigned pkbf(float a, float b) {
  unsigned r;
  asm("v_cvt_pk_bf16_f32 %0, %1, %2" : "=v"(r) : "v"(a), "v"(b));
  return r;
}

__global__ void cast_x_kernel(const float* __restrict__ x, short* __restrict__ xb, int total) {
  int i = blockIdx.x * 256 + threadIdx.x;
  if (i < total) xb[i] = f2bf(x[i]);
}

// pack w[K][N] (f32) -> p[(k>>3)][n][k&7] (bf16)
__global__ void pack_w_kernel(const float* __restrict__ w, short* __restrict__ p, int K, int N) {
  int idx = blockIdx.x * 256 + threadIdx.x;
  if (idx >= K * N) return;
  int k = idx / N, n = idx - k * N;
  p[(size_t)(k >> 3) * N * 8 + (size_t)n * 8 + (k & 7)] = f2bf(w[idx]);
}

// ---------------- CSR build ----------------
__global__ void hist_kernel(const int* __restrict__ ei, int* __restrict__ deg) {
  int e = blockIdx.x * 256 + threadIdx.x;
  if (e < NEDGE) {
    int j = ei[NEDGE + e]; j = min(max(j, 0), NNODE - 1);
    atomicAdd(&deg[j], 1);
  }
}

__global__ void scan_kernel(const int* __restrict__ deg, int* __restrict__ row_start) {
  __shared__ int part[256];
  int t = threadIdx.x;
  const int CH = 40;
  int base = t * CH;
  int s = 0;
  for (int i = 0; i < CH; i++) {
    int idx = base + i;
    s += (idx < NNODE) ? deg[idx] : 0;
  }
  part[t] = s;
  __syncthreads();
  for (int off = 1; off < 256; off <<= 1) {
    int v = (t >= off) ? part[t - off] : 0;
    __syncthreads();
    part[t] += v;
    __syncthreads();
  }
  int run = (t == 0) ? 0 : part[t - 1];
  for (int i = 0; i < CH; i++) {
    int idx = base + i;
    if (idx < NNODE) { row_start[idx] = run; run += deg[idx]; }
  }
  if (t == 255) row_start[NNODE] = part[255];
}

__global__ void scatter_kernel(const int* __restrict__ ei, const int* __restrict__ row_start,
                               int* __restrict__ cursor, int* __restrict__ csr) {
  int e = blockIdx.x * 256 + threadIdx.x;
  if (e < NEDGE) {
    int j = ei[NEDGE + e]; j = min(max(j, 0), NNODE - 1);
    int p = atomicAdd(&cursor[j], 1);
    csr[row_start[j] + p] = e;
  }
}

__global__ __launch_bounds__(256) void agg_kernel(const float* __restrict__ out_e,
                                                  const int* __restrict__ row_start,
                                                  const int* __restrict__ csr,
                                                  short* __restrict__ aggb) {
  int node = blockIdx.x * 4 + (threadIdx.x >> 6);
  int lane = threadIdx.x & 63;
  if (node >= NNODE) return;
  int rs = row_start[node], re = row_start[node + 1];
  float4 acc = {0.f, 0.f, 0.f, 0.f};
  for (int k = rs; k < re; k++) {
    int eid = csr[k];
    float4 v = *(const float4*)(out_e + (size_t)eid * DD + lane * 4);
    acc.x += v.x; acc.y += v.y; acc.z += v.z; acc.w += v.w;
  }
  short4 o;
  o.x = f2bf(acc.x); o.y = f2bf(acc.y); o.z = f2bf(acc.z); o.w = f2bf(acc.w);
  *(short4*)(aggb + (size_t)node * DD + lane * 4) = o;
}

// MODE 0: edge (K1=768, A = x[i] | x[j] | ea, residual=ea)
// MODE 1: node (K1=512, A = x | agg(bf16), residual=x)
// A staged async (global_load_lds w16) into XOR-swizzled double buffer; GEMM1 in
// 2 column-passes (acc1=64); GEMM2 accumulates k-partials per pass; LN in-register.
template<int MODE>
__global__ __launch_bounds__(256, 3)
void fused_mlp(const float* __restrict__ x,
               const short* __restrict__ xb,
               const int*   __restrict__ ei,
               const float* __restrict__ ea,
               const short* __restrict__ aggb,
               const short* __restrict__ w1p,
               const float* __restrict__ b1,
               const short* __restrict__ w2p,
               const float* __restrict__ b2,
               const float* __restrict__ gam,
               const float* __restrict__ bet,
               float*       __restrict__ out)
{
  constexpr int K1  = (MODE == 0) ? 768 : 512;
  constexpr int NST = K1 / 64;      // stages per pass (12 | 8)
  constexpr int HP  = 264;          // hidden pitch (bf16)

  __shared__ __align__(16) short abuf[2][4096];   // 2 x [64 rows][64 k] bf16, swizzled
  __shared__ __align__(16) short hid[64 * HP];    // 33,792 B
  __shared__ int idxi[64], idxj[64];
  __shared__ float pS[4][64], pQ[4][64];

  const int tid  = threadIdx.x;
  const int lane = tid & 63;
  const int wid  = tid >> 6;
  const int m0   = blockIdx.x * 64;
  const int lhi  = lane >> 4;
  const int llo  = lane & 15;

  if (MODE == 0) {
    if (tid < 64) {
      int a = ei[m0 + tid];
      int b = ei[NEDGE + m0 + tid];
      idxi[tid] = min(max(a, 0), NNODE - 1);
      idxj[tid] = min(max(b, 0), NNODE - 1);
    }
    __syncthreads();
  }

  // Per-lane staging geometry. Chunk c = it*256 + tid -> row = c>>3, seg0 = c&7.
  // Swizzle: this lane fetches global k-window seg = seg0 ^ (row&7), so that
  // ds_read at row*128B + (seg_r^(row&7))*16B finds k-seg seg_r. (both-sides XOR)
  const int row0 = tid >> 3;        // it=0 rows 0..31
  const int row1 = 32 + (tid >> 3); // it=1 rows 32..63
  const int es0 = (((tid & 7) ^ (row0 & 7)) * 8);  // elem offset in 64-k window
  const int es1 = (((tid & 7) ^ (row1 & 7)) * 8);
  int offI0, offI1, offJ0, offJ1, offE0, offE1;
  if (MODE == 0) {
    offI0 = idxi[row0] * 512 + es0 * 2;  offI1 = idxi[row1] * 512 + es1 * 2;
    offJ0 = idxj[row0] * 512 + es0 * 2;  offJ1 = idxj[row1] * 512 + es1 * 2;
    offE0 = (m0 + row0) * 1024 + es0 * 4; offE1 = (m0 + row1) * 1024 + es1 * 4;
  } else {
    int r0 = min(m0 + row0, NNODE - 1), r1 = min(m0 + row1, NNODE - 1);
    offI0 = r0 * 512 + es0 * 2;  offI1 = r1 * 512 + es1 * 2;
    offJ0 = r0 * 512 + es0 * 2;  offJ1 = r1 * 512 + es1 * 2;
    offE0 = 0; offE1 = 0;
  }

  auto STAGE = [&](int buf, int k0) {
    if (MODE == 1 || k0 < 512) {
      const char* base;
      int o0, o1;
      if (k0 < 256) {
        base = (const char*)xb;
        o0 = offI0 + k0 * 2; o1 = offI1 + k0 * 2;
      } else {
        base = (MODE == 0) ? (const char*)xb : (const char*)aggb;
        o0 = offJ0 + (k0 - 256) * 2; o1 = offJ1 + (k0 - 256) * 2;
      }
      __builtin_amdgcn_global_load_lds((const int*)(base + o0),
                                       (int*)&abuf[buf][wid * 512], 16, 0, 0);
      __builtin_amdgcn_global_load_lds((const int*)(base + o1),
                                       (int*)&abuf[buf][2048 + wid * 512], 16, 0, 0);
    } else {
      // edge_attr segment: f32 -> bf16 reg-staged (same swizzled mapping)
      const char* eb = (const char*)ea;
      const float4* f0 = (const float4*)(eb + offE0 + (k0 - 512) * 4);
      const float4* f1 = (const float4*)(eb + offE1 + (k0 - 512) * 4);
      float4 a0 = f0[0], a1 = f0[1];
      float4 c0 = f1[0], c1 = f1[1];
      u32x4 q0 = { pkbf(a0.x, a0.y), pkbf(a0.z, a0.w), pkbf(a1.x, a1.y), pkbf(a1.z, a1.w) };
      u32x4 q1 = { pkbf(c0.x, c0.y), pkbf(c0.z, c0.w), pkbf(c1.x, c1.y), pkbf(c1.z, c1.w) };
      *(u32x4*)&abuf[buf][tid * 8]        = q0;
      *(u32x4*)&abuf[buf][2048 + tid * 8] = q1;
    }
  };

  f32x4 acc1[4][4];
  f32x4 acc2[4][4];
  #pragma unroll
  for (int a = 0; a < 4; a++)
    #pragma unroll
    for (int b = 0; b < 4; b++)
      #pragma unroll
      for (int r = 0; r < 4; r++) { acc1[a][b][r] = 0.f; acc2[a][b][r] = 0.f; }

  const bf16x8* bp1 = (const bf16x8*)w1p;
  const bf16x8* bp2 = (const bf16x8*)w2p;
  const int swz = llo & 7;

  STAGE(0, 0);
  __syncthreads();

  #pragma unroll
  for (int p = 0; p < 2; p++) {
    // ---------------- GEMM1 pass p: [64 x K1] @ [K1 x 256] ----------------
    #pragma unroll 2
    for (int s = 0; s < NST; s++) {
      if (s < NST - 1) STAGE((s + 1) & 1, (s + 1) * 64);
      const short* ab = &abuf[s & 1][0];
      #pragma unroll
      for (int kk = 0; kk < 64; kk += 32) {
        bf16x8 a[4];
        const int seg = ((kk >> 3) + lhi) ^ swz;
        #pragma unroll
        for (int mf = 0; mf < 4; mf++)
          a[mf] = *(const bf16x8*)(ab + (mf * 16 + llo) * 64 + seg * 8);
        const bf16x8* bb = bp1 + (size_t)(s * 8 + (kk >> 3) + lhi) * 512
                               + (p * 256 + wid * 64 + llo);
        #pragma unroll
        for (int nf = 0; nf < 4; nf++) {
          bf16x8 b = bb[nf * 16];
          #pragma unroll
          for (int mf = 0; mf < 4; mf++)
            acc1[mf][nf] = __builtin_amdgcn_mfma_f32_16x16x32_bf16(a[mf], b, acc1[mf][nf], 0, 0, 0);
        }
      }
      __syncthreads();
    }

    // bias + relu -> hid (pass-local cols 0..255); reset acc1
    #pragma unroll
    for (int nf = 0; nf < 4; nf++) {
      int col = wid * 64 + nf * 16 + llo;
      float bb = b1[p * 256 + col];
      #pragma unroll
      for (int mf = 0; mf < 4; mf++) {
        #pragma unroll
        for (int r = 0; r < 4; r++) {
          float v = acc1[mf][nf][r] + bb;
          v = v > 0.f ? v : 0.f;
          hid[(mf * 16 + lhi * 4 + r) * HP + col] = f2bf(v);
          acc1[mf][nf][r] = 0.f;
        }
      }
    }
    __syncthreads();

    if (p == 0) STAGE(0, 0);  // prefetch pass-1 stage-0 under GEMM2

    // ---------------- GEMM2 partial: k = p*256 .. p*256+255 ----------------
    #pragma unroll 2
    for (int kk = 0; kk < 256; kk += 32) {
      bf16x8 a[4];
      #pragma unroll
      for (int mf = 0; mf < 4; mf++)
        a[mf] = *(const bf16x8*)(hid + (mf * 16 + llo) * HP + kk + lhi * 8);
      const bf16x8* bb = bp2 + (size_t)(p * 32 + (kk >> 3) + lhi) * 256 + (wid * 64 + llo);
      #pragma unroll
      for (int nf = 0; nf < 4; nf++) {
        bf16x8 b = bb[nf * 16];
        #pragma unroll
        for (int mf = 0; mf < 4; mf++)
          acc2[mf][nf] = __builtin_amdgcn_mfma_f32_16x16x32_bf16(a[mf], b, acc2[mf][nf], 0, 0, 0);
      }
    }
    __syncthreads();
  }

  // ---------------- LayerNorm in registers ----------------
  const int bcol2 = wid * 64 + llo;
  float bb2[4], gg[4], be[4];
  #pragma unroll
  for (int nf = 0; nf < 4; nf++) {
    int col = bcol2 + nf * 16;
    bb2[nf] = b2[col]; gg[nf] = gam[col]; be[nf] = bet[col];
  }
  #pragma unroll
  for (int mf = 0; mf < 4; mf++)
    #pragma unroll
    for (int nf = 0; nf < 4; nf++)
      #pragma unroll
      for (int r = 0; r < 4; r++)
        acc2[mf][nf][r] += bb2[nf];

  float S[4][4], Q[4][4];
  #pragma unroll
  for (int mf = 0; mf < 4; mf++) {
    #pragma unroll
    for (int r = 0; r < 4; r++) {
      float s = 0.f, q = 0.f;
      #pragma unroll
      for (int nf = 0; nf < 4; nf++) {
        float v = acc2[mf][nf][r];
        s += v; q += v * v;
      }
      S[mf][r] = s; Q[mf][r] = q;
    }
  }
  #pragma unroll
  for (int m = 1; m <= 8; m <<= 1) {
    #pragma unroll
    for (int mf = 0; mf < 4; mf++)
      #pragma unroll
      for (int r = 0; r < 4; r++) {
        S[mf][r] += __shfl_xor(S[mf][r], m);
        Q[mf][r] += __shfl_xor(Q[mf][r], m);
      }
  }
  if (llo == 0) {
    #pragma unroll
    for (int mf = 0; mf < 4; mf++)
      #pragma unroll
      for (int r = 0; r < 4; r++) {
        int row = mf * 16 + lhi * 4 + r;
        pS[wid][row] = S[mf][r];
        pQ[wid][row] = Q[mf][r];
      }
  }
  __syncthreads();

  float mu[4][4], rsv[4][4];
  #pragma unroll
  for (int mf = 0; mf < 4; mf++) {
    #pragma unroll
    for (int r = 0; r < 4; r++) {
      int row = mf * 16 + lhi * 4 + r;
      float s = pS[0][row] + pS[1][row] + pS[2][row] + pS[3][row];
      float q = pQ[0][row] + pQ[1][row] + pQ[2][row] + pQ[3][row];
      float m_ = s * (1.f / 256.f);
      mu[mf][r]  = m_;
      rsv[mf][r] = rsqrtf(q * (1.f / 256.f) - m_ * m_ + 1e-5f);
    }
  }

  const float* resb = (MODE == 0) ? ea : x;
  #pragma unroll
  for (int mf = 0; mf < 4; mf++) {
    #pragma unroll
    for (int r = 0; r < 4; r++) {
      int grow = m0 + mf * 16 + lhi * 4 + r;
      if (MODE == 1 && grow >= NNODE) continue;
      const float* rp = resb + (size_t)grow * DD + bcol2;
      float*       op = out  + (size_t)grow * DD + bcol2;
      #pragma unroll
      for (int nf = 0; nf < 4; nf++) {
        float v = (acc2[mf][nf][r] - mu[mf][r]) * rsv[mf][r] * gg[nf] + be[nf] + rp[nf * 16];
        op[nf * 16] = v;
      }
    }
  }
}

extern "C" void kernel_launch(void* const* d_in, const int* in_sizes, int n_in,
                              void* d_out, int out_size, void* d_ws, size_t ws_size,
                              hipStream_t stream) {
  const float* x      = (const float*)d_in[0];
  const int*   ei     = (const int*)  d_in[1];
  const float* ea     = (const float*)d_in[2];
  const float* e_w1   = (const float*)d_in[3];
  const float* e_b1   = (const float*)d_in[4];
  const float* e_w2   = (const float*)d_in[5];
  const float* e_b2   = (const float*)d_in[6];
  const float* e_g    = (const float*)d_in[7];
  const float* e_beta = (const float*)d_in[8];
  const float* n_w1   = (const float*)d_in[9];
  const float* n_b1   = (const float*)d_in[10];
  const float* n_w2   = (const float*)d_in[11];
  const float* n_b2   = (const float*)d_in[12];
  const float* n_g    = (const float*)d_in[13];
  const float* n_beta = (const float*)d_in[14];

  float* out_x = (float*)d_out;
  float* out_e = (float*)d_out + (size_t)NNODE * DD;

  char* w = (char*)d_ws;
  short* xb   = (short*)(w);                    // 5,120,000 B
  short* ew1p = (short*)(w + 5120000);          //   786,432 B
  short* nw1p = (short*)(w + 5906432);          //   524,288 B
  short* ew2p = (short*)(w + 6430720);          //   262,144 B
  short* nw2p = (short*)(w + 6692864);          //   262,144 B
  short* aggb = (short*)(w + 6955008);          // 5,120,000 B
  int*   deg  = (int*)  (w + 12075008);         //    40,960 B
  int*   cur  = (int*)  (w + 12115968);         //    40,960 B
  int*   rs   = (int*)  (w + 12156928);         //    40,976 B
  int*   csr  = (int*)  (w + 12197904);         //   640,000 B

  hipMemsetAsync(deg, 0, 81920, stream);  // deg + cursor

  cast_x_kernel<<<(NNODE * DD + 255) / 256, 256, 0, stream>>>(x, xb, NNODE * DD);
  pack_w_kernel<<<(768 * 512 + 255) / 256, 256, 0, stream>>>(e_w1, ew1p, 768, 512);
  pack_w_kernel<<<(512 * 512 + 255) / 256, 256, 0, stream>>>(n_w1, nw1p, 512, 512);
  pack_w_kernel<<<(512 * 256 + 255) / 256, 256, 0, stream>>>(e_w2, ew2p, 512, 256);
  pack_w_kernel<<<(512 * 256 + 255) / 256, 256, 0, stream>>>(n_w2, nw2p, 512, 256);

  hist_kernel<<<(NEDGE + 255) / 256, 256, 0, stream>>>(ei, deg);
  scan_kernel<<<1, 256, 0, stream>>>(deg, rs);
  scatter_kernel<<<(NEDGE + 255) / 256, 256, 0, stream>>>(ei, rs, cur, csr);

  fused_mlp<0><<<NEDGE / 64, 256, 0, stream>>>(x, xb, ei, ea, aggb,
                                               ew1p, e_b1, ew2p, e_b2, e_g, e_beta, out_e);
  agg_kernel<<<(NNODE + 3) / 4, 256, 0, stream>>>(out_e, rs, csr, aggb);
  fused_mlp<1><<<(NNODE + 63) / 64, 256, 0, stream>>>(x, xb, ei, ea, aggb,
                                                      nw1p, n_b1, nw2p, n_b2, n_g, n_beta, out_x);
}